// Round 16
// baseline (231.035 us; speedup 1.0000x reference)
//
#include <hip/hip_runtime.h>
#include <hip/hip_bf16.h>

#define NSP 4096
#define BEPS 1e-5f
#define JSPLIT 4
#define JCHUNK (NSP / JSPLIT)

using short8  = __attribute__((ext_vector_type(8))) short;
using f32x4   = __attribute__((ext_vector_type(4))) float;

// scale * log2(e) : softmax exp(s*scale) == exp2(s*SCALE_LOG2E)
#define SCALE_LOG2E 0.25500526940103816f

__device__ __forceinline__ float b2f(unsigned short u) {
  return __uint_as_float(((unsigned)u) << 16);
}
__device__ __forceinline__ float b2f_lo(unsigned w) {
  return __uint_as_float(w << 16);
}
__device__ __forceinline__ float b2f_hi(unsigned w) {
  return __uint_as_float(w & 0xffff0000u);
}
// float -> bf16 bits, round-nearest-even (manual; non-hot paths)
__device__ __forceinline__ unsigned short f2b(float x) {
  unsigned u = __float_as_uint(x);
  u += 0x7fffu + ((u >> 16) & 1u);
  return (unsigned short)(u >> 16);
}
// HW packed convert: v_cvt_pk_bf16_f32 on gfx950 (1 inst vs ~10 manual)
__device__ __forceinline__ unsigned pk2u(float a, float b) {
  __hip_bfloat162 h = __float22bfloat162_rn(float2{a, b});
  unsigned r;
  __builtin_memcpy(&r, &h, sizeof(r));
  return r;
}

// ---------------- Kernel 0: transpose-cast x -> xT (b, n, c) bf16 ----------------
__global__ __launch_bounds__(256) void transpose_x_kernel(
    const float* __restrict__ x, unsigned short* __restrict__ xT)
{
  const int n0 = blockIdx.x * 64, c0 = blockIdx.y * 64, b = blockIdx.z;
  __shared__ __align__(16) unsigned short tx[64][72];   // [n][c]
  const int t = threadIdx.x;
  const int row = t >> 2;        // c index within tile
  const int seg = t & 3;         // 16 n each
  {
    const float* xp = x + ((size_t)(b * 256 + c0 + row)) * NSP + n0 + seg * 16;
    #pragma unroll
    for (int q4 = 0; q4 < 4; ++q4) {
      const float4 a = *reinterpret_cast<const float4*>(xp + q4 * 4);
      tx[seg * 16 + q4 * 4 + 0][row] = f2b(a.x);
      tx[seg * 16 + q4 * 4 + 1][row] = f2b(a.y);
      tx[seg * 16 + q4 * 4 + 2][row] = f2b(a.z);
      tx[seg * 16 + q4 * 4 + 3][row] = f2b(a.w);
    }
  }
  __syncthreads();
  const int nrow = t >> 2, ch = t & 3;
  unsigned short* op = xT + ((size_t)(b * NSP + n0 + nrow)) * 256 + c0 + ch * 16;
  *reinterpret_cast<float4*>(op)     = *reinterpret_cast<const float4*>(&tx[nrow][ch * 16]);
  *reinterpret_cast<float4*>(op + 8) = *reinterpret_cast<const float4*>(&tx[nrow][ch * 16 + 8]);
}

// ---------------- Kernel 1: MFMA qkv GEMM + BN + scatter (128-n tiles) ----------------
// W staged directly from fp32 with inline v_cvt_pk_bf16_f32 (no prep kernel).
// q rows: BN scale/bias pre-multiplied by SCALE_LOG2E so attn's softmax needs no mul.
__global__ __launch_bounds__(256) void qkv_gemm_kernel(
    const unsigned short* __restrict__ xT, const float* __restrict__ qkv_w,
    const float* __restrict__ gg, const float* __restrict__ bb,
    const float* __restrict__ mm, const float* __restrict__ vv,
    unsigned short* __restrict__ qb, unsigned short* __restrict__ kb,
    unsigned short* __restrict__ vb)
{
  const int n0 = blockIdx.x * 128;
  const int cotile = blockIdx.y;           // 8 tiles of 64 co
  const int b = blockIdx.z;
  const int co0 = cotile * 64;
  const int t = threadIdx.x;
  __shared__ __align__(16) unsigned short wt[64][136];    // [co][k-chunk 128]
  __shared__ __align__(16) unsigned short xt[128][136];   // [n][k-chunk 128]
  const int lane = t & 63, wave = t >> 6;
  const int m16 = lane & 15, quad = lane >> 4;

  f32x4 acc[8] = {};
  for (int kc = 0; kc < 2; ++kc) {
    if (kc) __syncthreads();
    {
      const float* wp = qkv_w + (size_t)(co0 + (t >> 2)) * 256 + kc * 128 + (t & 3) * 32;
      #pragma unroll
      for (int u = 0; u < 4; ++u) {
        const float4 a = *reinterpret_cast<const float4*>(wp + u * 8);
        const float4 c = *reinterpret_cast<const float4*>(wp + u * 8 + 4);
        uint4 w4;
        w4.x = pk2u(a.x, a.y); w4.y = pk2u(a.z, a.w);
        w4.z = pk2u(c.x, c.y); w4.w = pk2u(c.z, c.w);
        *reinterpret_cast<uint4*>(&wt[t >> 2][(t & 3) * 32 + u * 8]) = w4;
      }
      const unsigned short* xp = xT + ((size_t)(b * NSP + n0 + (t >> 1))) * 256 + kc * 128 + (t & 1) * 64;
      #pragma unroll
      for (int u = 0; u < 8; ++u)
        *reinterpret_cast<float4*>(&xt[t >> 1][(t & 1) * 64 + u * 8]) =
            *reinterpret_cast<const float4*>(xp + u * 8);
    }
    __syncthreads();
    if ((cotile & 1) == 0) {   // q/k: A = W (m=co), B = X (n=spatial)
      #pragma unroll
      for (int ks = 0; ks < 4; ++ks) {
        const short8 af = *reinterpret_cast<const short8*>(&wt[wave * 16 + m16][ks * 32 + quad * 8]);
        #pragma unroll
        for (int nt = 0; nt < 8; ++nt) {
          const short8 bf = *reinterpret_cast<const short8*>(&xt[nt * 16 + m16][ks * 32 + quad * 8]);
          acc[nt] = __builtin_amdgcn_mfma_f32_16x16x32_bf16(af, bf, acc[nt], 0, 0, 0);
        }
      }
    } else {                   // v: swapped -> A = X (m=spatial), B = W (n=co)
      #pragma unroll
      for (int ks = 0; ks < 4; ++ks) {
        const short8 bf = *reinterpret_cast<const short8*>(&wt[wave * 16 + m16][ks * 32 + quad * 8]);
        #pragma unroll
        for (int nt = 0; nt < 8; ++nt) {
          const short8 af = *reinterpret_cast<const short8*>(&xt[nt * 16 + m16][ks * 32 + quad * 8]);
          acc[nt] = __builtin_amdgcn_mfma_f32_16x16x32_bf16(af, bf, acc[nt], 0, 0, 0);
        }
      }
    }
  }

  const int head = cotile >> 1;
  const int bh = b * 4 + head;
  if ((cotile & 1) == 0) {
    const int coh = wave * 16 + quad * 4;   // 0..63 within head half (q if <32 else k)
    const bool isq = (coh < 32);
    const float fold = isq ? SCALE_LOG2E : 1.0f;   // pre-scale q for softmax exp2
    float sc[4], bi[4];
    #pragma unroll
    for (int r = 0; r < 4; ++r) {
      const int c = co0 + coh + r;
      const float s0 = gg[c] * rsqrtf(vv[c] + BEPS);
      sc[r] = s0 * fold;
      bi[r] = (bb[c] - mm[c] * s0) * fold;
    }
    unsigned short* dst = isq ? qb : kb;
    const int d0 = coh & 31;
    #pragma unroll
    for (int nt = 0; nt < 8; ++nt) {
      const int i = n0 + nt * 16 + m16;
      uint2 pk2;
      pk2.x = pk2u(acc[nt][0] * sc[0] + bi[0], acc[nt][1] * sc[1] + bi[1]);
      pk2.y = pk2u(acc[nt][2] * sc[2] + bi[2], acc[nt][3] * sc[3] + bi[3]);
      *reinterpret_cast<uint2*>(dst + ((size_t)bh * NSP + i) * 32 + d0) = pk2;
    }
  } else {
    const int c = co0 + wave * 16 + m16;
    const float sc = gg[c] * rsqrtf(vv[c] + BEPS);
    const float bi = bb[c] - mm[c] * sc;
    const int d = wave * 16 + m16;
    #pragma unroll
    for (int nt = 0; nt < 8; ++nt) {
      const int j = n0 + nt * 16 + quad * 4;
      uint2 pk2;
      pk2.x = pk2u(acc[nt][0] * sc + bi, acc[nt][1] * sc + bi);
      pk2.y = pk2u(acc[nt][2] * sc + bi, acc[nt][3] * sc + bi);
      *reinterpret_cast<uint2*>(vb + ((size_t)(bh * 64 + d)) * NSP + j) = pk2;
    }
  }
}

// ---------------- Kernel 2: MFMA flash attention (r13 structure, 5 blocks/CU) ----------
// 128-i tiles, reg-prefetch dbuf, Q pre-scaled, HW packed converts, ps LDS round-trip.
// (256,5): LDS 32KB x 5 = 160KB exactly; kernel uses ~64 VGPR << 102 cap -> no spill.
__global__ __launch_bounds__(256, 5) void attn_kernel(
    const unsigned short* __restrict__ qb, const unsigned short* __restrict__ kb,
    const unsigned short* __restrict__ vb,
    unsigned short* __restrict__ Opart, float* __restrict__ lpart)
{
  const int i0    = blockIdx.x * 128;
  const int bh    = blockIdx.y;
  const int split = blockIdx.z;
  const int jbase = split * JCHUNK;
  const int t  = threadIdx.x;
  const int lane = t & 63, wave = t >> 6;
  const int m16 = lane & 15, quad = lane >> 4;
  __shared__ __align__(16) short smem[16384];       // 32 KB
  short (*qs)[40] = (short(*)[40])smem;             // [i][d]  128x40 (first 10.2KB)
  short (*ps)[72] = (short(*)[72])smem;             // [i][j]  128x72 (overlays qs, 18KB)
  short (*ks)[40] = (short(*)[40])(smem + 9216);    // [j][d]  64x40
  short (*vs)[72] = (short(*)[72])(smem + 9216 + 2560);  // [d][j] 64x72

  {  // stage Q once: 128 rows x 32 bf16 (each thread 32B)
    const unsigned short* qp = qb + ((size_t)bh * NSP + i0) * 32;
    const int r = t >> 1, h = t & 1;
    *reinterpret_cast<float4*>(&qs[r][h * 16]) =
        *reinterpret_cast<const float4*>(qp + r * 32 + h * 16);
    *reinterpret_cast<float4*>(&qs[r][h * 16 + 8]) =
        *reinterpret_cast<const float4*>(qp + r * 32 + h * 16 + 8);
  }
  __syncthreads();
  short8 qfrag[2];
  qfrag[0] = *reinterpret_cast<const short8*>(&qs[wave * 32 + m16][quad * 8]);
  qfrag[1] = *reinterpret_cast<const short8*>(&qs[wave * 32 + 16 + m16][quad * 8]);

  float rsum[2] = {0.f, 0.f};
  f32x4 oacc[2][4] = {};

  const int srow = t >> 2, schunk = t & 3;
  const unsigned short* kbase = kb + (size_t)bh * NSP * 32;
  const unsigned short* vbase = vb + (size_t)bh * 64 * NSP;

  // prologue: tile 0 -> regs -> LDS
  float4 kreg, vreg0, vreg1;
  kreg  = *reinterpret_cast<const float4*>(kbase + (size_t)(jbase + srow) * 32 + schunk * 8);
  vreg0 = *reinterpret_cast<const float4*>(vbase + (size_t)srow * NSP + jbase + schunk * 16);
  vreg1 = *reinterpret_cast<const float4*>(vbase + (size_t)srow * NSP + jbase + schunk * 16 + 8);
  *reinterpret_cast<float4*>(&ks[srow][schunk * 8]) = kreg;
  *reinterpret_cast<float4*>(&vs[srow][schunk * 16]) = vreg0;
  *reinterpret_cast<float4*>(&vs[srow][schunk * 16 + 8]) = vreg1;
  __syncthreads();   // tile 0 visible; all waves past qfrag extraction (ps overlay safe)

  for (int jt0 = 0; jt0 < JCHUNK; jt0 += 64) {
    const bool more = (jt0 + 64) < JCHUNK;
    if (more) {   // prefetch tile j+1 into regs; latency overlaps compute below
      const int jn = jbase + jt0 + 64;
      kreg  = *reinterpret_cast<const float4*>(kbase + (size_t)(jn + srow) * 32 + schunk * 8);
      vreg0 = *reinterpret_cast<const float4*>(vbase + (size_t)srow * NSP + jn + schunk * 16);
      vreg1 = *reinterpret_cast<const float4*>(vbase + (size_t)srow * NSP + jn + schunk * 16 + 8);
    }

    // K fragments once, reused for both i-halves
    short8 kf[4];
    #pragma unroll
    for (int jt = 0; jt < 4; ++jt)
      kf[jt] = *reinterpret_cast<const short8*>(&ks[jt * 16 + m16][quad * 8]);

    #pragma unroll
    for (int it = 0; it < 2; ++it) {
      // S^T sub-tile: A = K (m=j), B = Q (n=i) -> lane holds i, rows j.
      f32x4 sacc[4];
      #pragma unroll
      for (int jt = 0; jt < 4; ++jt)
        sacc[jt] = __builtin_amdgcn_mfma_f32_16x16x32_bf16(kf[jt], qfrag[it],
                                                           (f32x4){0.f,0.f,0.f,0.f}, 0, 0, 0);
      const int irow = wave * 32 + it * 16 + m16;
      #pragma unroll
      for (int jt = 0; jt < 4; ++jt) {
        float p0 = __builtin_amdgcn_exp2f(sacc[jt][0]);
        float p1 = __builtin_amdgcn_exp2f(sacc[jt][1]);
        float p2 = __builtin_amdgcn_exp2f(sacc[jt][2]);
        float p3 = __builtin_amdgcn_exp2f(sacc[jt][3]);
        rsum[it] += (p0 + p1) + (p2 + p3);
        uint2 pk2;
        pk2.x = pk2u(p0, p1);
        pk2.y = pk2u(p2, p3);
        *reinterpret_cast<uint2*>(&ps[irow][jt * 16 + quad * 4]) = pk2;
      }
    }

    // PV: O[i][d] += P[i][j] V[j][d]; V-frags reused for both i-halves.
    short8 pa[2][2];
    #pragma unroll
    for (int it = 0; it < 2; ++it) {
      pa[it][0] = *reinterpret_cast<const short8*>(&ps[wave * 32 + it * 16 + m16][quad * 8]);
      pa[it][1] = *reinterpret_cast<const short8*>(&ps[wave * 32 + it * 16 + m16][32 + quad * 8]);
    }
    #pragma unroll
    for (int dt = 0; dt < 4; ++dt) {
      const short8 v0 = *reinterpret_cast<const short8*>(&vs[dt * 16 + m16][quad * 8]);
      const short8 v1 = *reinterpret_cast<const short8*>(&vs[dt * 16 + m16][32 + quad * 8]);
      #pragma unroll
      for (int it = 0; it < 2; ++it) {
        oacc[it][dt] = __builtin_amdgcn_mfma_f32_16x16x32_bf16(pa[it][0], v0, oacc[it][dt], 0, 0, 0);
        oacc[it][dt] = __builtin_amdgcn_mfma_f32_16x16x32_bf16(pa[it][1], v1, oacc[it][dt], 0, 0, 0);
      }
    }

    if (more) {   // commit prefetched tile to LDS
      __syncthreads();   // all reads of ks/vs for tile j done
      *reinterpret_cast<float4*>(&ks[srow][schunk * 8]) = kreg;
      *reinterpret_cast<float4*>(&vs[srow][schunk * 16]) = vreg0;
      *reinterpret_cast<float4*>(&vs[srow][schunk * 16 + 8]) = vreg1;
      __syncthreads();   // tile j+1 visible
    }
  }

  // finalize l for this block's j-range: reduce across quads (same m16)
  #pragma unroll
  for (int it = 0; it < 2; ++it) {
    float rs = rsum[it];
    rs += __shfl_xor(rs, 16);
    rs += __shfl_xor(rs, 32);
    if (quad == 0)
      lpart[((size_t)split * 8 + bh) * NSP + i0 + wave * 32 + it * 16 + m16] = rs;
  }

  // store unnormalized O partial as bf16: [split][bh][d][i], 4 consecutive i -> 8B
  #pragma unroll
  for (int it = 0; it < 2; ++it)
    #pragma unroll
    for (int dt = 0; dt < 4; ++dt) {
      const int d = dt * 16 + m16;
      uint2 pk2;
      pk2.x = pk2u(oacc[it][dt][0], oacc[it][dt][1]);
      pk2.y = pk2u(oacc[it][dt][2], oacc[it][dt][3]);
      *reinterpret_cast<uint2*>(Opart +
          (((size_t)split * 8 + bh) * 64 + d) * NSP + i0 + wave * 32 + it * 16 + quad * 4) = pk2;
    }
}

// ---------------- Kernel 3: fused combine + pe -> yT (b, n, c) bf16 (vectorized) --------
__global__ __launch_bounds__(256) void fuse_kernel(
    const unsigned short* __restrict__ Opart, const float* __restrict__ lpart,
    const unsigned short* __restrict__ vb,
    const float* __restrict__ pw, const float* __restrict__ pg,
    const float* __restrict__ pb, const float* __restrict__ pm,
    const float* __restrict__ pv,
    unsigned short* __restrict__ yT)
{
  const int py = blockIdx.x;       // spatial row
  const int bh = blockIdx.y;       // 8
  const int b = bh >> 2, h = bh & 3;
  const int t = threadIdx.x;
  const int d = t >> 2, seg = t & 3;      // d 0..63 ; px window = seg*16..+15
  __shared__ float lsum[64];
  __shared__ __align__(16) unsigned short yt[64][72];   // [px][d]

  if (t < 64) {
    float ls = 0.f;
    #pragma unroll
    for (int s = 0; s < JSPLIT; ++s)
      ls += lpart[((size_t)s * 8 + bh) * NSP + py * 64 + t];
    lsum[t] = ls;
  }
  __syncthreads();

  const int c = h * 64 + d;
  const int i0 = py * 64 + seg * 16;
  float os[16] = {};
  #pragma unroll
  for (int s = 0; s < JSPLIT; ++s) {
    const uint4* op = reinterpret_cast<const uint4*>(
        Opart + (((size_t)s * 8 + bh) * 64 + d) * NSP + i0);
    const uint4 a = op[0], e = op[1];
    os[0]  += b2f_lo(a.x); os[1]  += b2f_hi(a.x);
    os[2]  += b2f_lo(a.y); os[3]  += b2f_hi(a.y);
    os[4]  += b2f_lo(a.z); os[5]  += b2f_hi(a.z);
    os[6]  += b2f_lo(a.w); os[7]  += b2f_hi(a.w);
    os[8]  += b2f_lo(e.x); os[9]  += b2f_hi(e.x);
    os[10] += b2f_lo(e.y); os[11] += b2f_hi(e.y);
    os[12] += b2f_lo(e.z); os[13] += b2f_hi(e.z);
    os[14] += b2f_lo(e.w); os[15] += b2f_hi(e.w);
  }

  float w9[9];
  #pragma unroll
  for (int i = 0; i < 9; ++i) w9[i] = pw[c * 9 + i];
  const float sc = pg[c] * rsqrtf(pv[c] + BEPS);
  const float bi = pb[c] - pm[c] * sc;
  const unsigned short* vrow = vb + ((size_t)(bh * 64 + d)) * NSP;

  float conv[16] = {};
  #pragma unroll
  for (int dy = -1; dy <= 1; ++dy) {
    const int yy = py + dy;
    if (yy < 0 || yy > 63) continue;
    const unsigned short* vr = vrow + yy * 64 + seg * 16;
    float vals[18];
    const uint4 m0 = *reinterpret_cast<const uint4*>(vr);
    const uint4 m1 = *reinterpret_cast<const uint4*>(vr + 8);
    vals[1]  = b2f_lo(m0.x); vals[2]  = b2f_hi(m0.x);
    vals[3]  = b2f_lo(m0.y); vals[4]  = b2f_hi(m0.y);
    vals[5]  = b2f_lo(m0.z); vals[6]  = b2f_hi(m0.z);
    vals[7]  = b2f_lo(m0.w); vals[8]  = b2f_hi(m0.w);
    vals[9]  = b2f_lo(m1.x); vals[10] = b2f_hi(m1.x);
    vals[11] = b2f_lo(m1.y); vals[12] = b2f_hi(m1.y);
    vals[13] = b2f_lo(m1.z); vals[14] = b2f_hi(m1.z);
    vals[15] = b2f_lo(m1.w); vals[16] = b2f_hi(m1.w);
    vals[0]  = (seg > 0) ? b2f_hi(*reinterpret_cast<const unsigned*>(vr - 2)) : 0.f;
    vals[17] = (seg < 3) ? b2f_lo(*reinterpret_cast<const unsigned*>(vr + 16)) : 0.f;
    const float wr0 = w9[(dy + 1) * 3 + 0], wr1 = w9[(dy + 1) * 3 + 1], wr2 = w9[(dy + 1) * 3 + 2];
    #pragma unroll
    for (int u = 0; u < 16; ++u)
      conv[u] += vals[u] * wr0 + vals[u + 1] * wr1 + vals[u + 2] * wr2;
  }

  #pragma unroll
  for (int u = 0; u < 16; ++u) {
    const float yv = os[u] / lsum[seg * 16 + u] + conv[u] * sc + bi;
    yt[seg * 16 + u][d] = f2b(yv);
  }
  __syncthreads();

  const int prow = t >> 2, ch = t & 3;
  unsigned short* op = yT + ((size_t)(b * NSP + py * 64 + prow)) * 256 + h * 64 + ch * 16;
  *reinterpret_cast<float4*>(op)     = *reinterpret_cast<const float4*>(&yt[prow][ch * 16]);
  *reinterpret_cast<float4*>(op + 8) = *reinterpret_cast<const float4*>(&yt[prow][ch * 16 + 8]);
}

// ---------------- Kernel 4: MFMA proj GEMM + BN -> out f32 (128-n tiles) ----------------
// W staged directly from fp32 with inline v_cvt_pk_bf16_f32 (no prep kernel).
__global__ __launch_bounds__(256) void proj_gemm_kernel(
    const unsigned short* __restrict__ yT, const float* __restrict__ proj_w,
    const float* __restrict__ gg, const float* __restrict__ bb,
    const float* __restrict__ mm, const float* __restrict__ vv,
    float* __restrict__ out)
{
  const int n0 = blockIdx.x * 128;
  const int co0 = blockIdx.y * 64;   // 4 tiles
  const int b = blockIdx.z;
  const int t = threadIdx.x;
  __shared__ __align__(16) unsigned short wt[64][136];
  __shared__ __align__(16) unsigned short yt[128][136];
  const int lane = t & 63, wave = t >> 6;
  const int m16 = lane & 15, quad = lane >> 4;

  f32x4 acc[8] = {};
  for (int kc = 0; kc < 2; ++kc) {
    if (kc) __syncthreads();
    {
      const float* wp = proj_w + (size_t)(co0 + (t >> 2)) * 256 + kc * 128 + (t & 3) * 32;
      #pragma unroll
      for (int u = 0; u < 4; ++u) {
        const float4 a = *reinterpret_cast<const float4*>(wp + u * 8);
        const float4 c = *reinterpret_cast<const float4*>(wp + u * 8 + 4);
        uint4 w4;
        w4.x = pk2u(a.x, a.y); w4.y = pk2u(a.z, a.w);
        w4.z = pk2u(c.x, c.y); w4.w = pk2u(c.z, c.w);
        *reinterpret_cast<uint4*>(&wt[t >> 2][(t & 3) * 32 + u * 8]) = w4;
      }
      const unsigned short* yp = yT + ((size_t)(b * NSP + n0 + (t >> 1))) * 256 + kc * 128 + (t & 1) * 64;
      #pragma unroll
      for (int u = 0; u < 8; ++u)
        *reinterpret_cast<float4*>(&yt[t >> 1][(t & 1) * 64 + u * 8]) =
            *reinterpret_cast<const float4*>(yp + u * 8);
    }
    __syncthreads();
    #pragma unroll
    for (int ks = 0; ks < 4; ++ks) {
      const short8 bf = *reinterpret_cast<const short8*>(&wt[wave * 16 + m16][ks * 32 + quad * 8]);
      #pragma unroll
      for (int nt = 0; nt < 8; ++nt) {
        const short8 af = *reinterpret_cast<const short8*>(&yt[nt * 16 + m16][ks * 32 + quad * 8]);
        acc[nt] = __builtin_amdgcn_mfma_f32_16x16x32_bf16(af, bf, acc[nt], 0, 0, 0);
      }
    }
  }

  const int c = co0 + wave * 16 + m16;
  const float sc = gg[c] * rsqrtf(vv[c] + BEPS);
  const float bi = bb[c] - mm[c] * sc;
  #pragma unroll
  for (int nt = 0; nt < 8; ++nt) {
    const int n = n0 + nt * 16 + quad * 4;
    float4 ov;
    ov.x = acc[nt][0] * sc + bi; ov.y = acc[nt][1] * sc + bi;
    ov.z = acc[nt][2] * sc + bi; ov.w = acc[nt][3] * sc + bi;
    *reinterpret_cast<float4*>(out + ((size_t)(b * 256 + c)) * NSP + n) = ov;
  }
}

extern "C" void kernel_launch(void* const* d_in, const int* in_sizes, int n_in,
                              void* d_out, int out_size, void* d_ws, size_t ws_size,
                              hipStream_t stream)
{
  const float* x      = (const float*)d_in[0];
  const float* qkv_w  = (const float*)d_in[1];
  const float* qkv_g  = (const float*)d_in[2];
  const float* qkv_b  = (const float*)d_in[3];
  const float* qkv_m  = (const float*)d_in[4];
  const float* qkv_v  = (const float*)d_in[5];
  const float* proj_w = (const float*)d_in[6];
  const float* proj_g = (const float*)d_in[7];
  const float* proj_b = (const float*)d_in[8];
  const float* proj_m = (const float*)d_in[9];
  const float* proj_v = (const float*)d_in[10];
  const float* pe_w   = (const float*)d_in[11];
  const float* pe_g   = (const float*)d_in[12];
  const float* pe_b   = (const float*)d_in[13];
  const float* pe_m   = (const float*)d_in[14];
  const float* pe_v   = (const float*)d_in[15];
  float* out = (float*)d_out;

  unsigned short* qb = (unsigned short*)d_ws;             // 2MB
  unsigned short* kb = qb + (size_t)8 * NSP * 32;         // 2MB
  unsigned short* vb = kb + (size_t)8 * NSP * 32;         // 4MB
  unsigned short* Opart = vb + (size_t)8 * 64 * NSP;      // 16MB
  float* lpart = (float*)(Opart + (size_t)JSPLIT * 8 * 64 * NSP);  // 512KB
  unsigned short* xT = (unsigned short*)(lpart + (size_t)JSPLIT * 8 * NSP);  // 4MB
  unsigned short* yT = xT + (size_t)2 * NSP * 256;        // 4MB

  transpose_x_kernel<<<dim3(64, 4, 2), 256, 0, stream>>>(x, xT);
  qkv_gemm_kernel<<<dim3(32, 8, 2), 256, 0, stream>>>(xT, qkv_w, qkv_g, qkv_b, qkv_m, qkv_v,
                                                      qb, kb, vb);
  attn_kernel<<<dim3(32, 8, JSPLIT), 256, 0, stream>>>(qb, kb, vb, Opart, lpart);
  fuse_kernel<<<dim3(64, 8), 256, 0, stream>>>(Opart, lpart, vb,
                                               pe_w, pe_g, pe_b, pe_m, pe_v, yT);
  proj_gemm_kernel<<<dim3(32, 4, 2), 256, 0, stream>>>(yT, proj_w, proj_g, proj_b, proj_m, proj_v,
                                                       out);
}

// Round 17
// 166.351 us; speedup vs baseline: 1.3888x; 1.3888x over previous
//
#include <hip/hip_runtime.h>
#include <hip/hip_bf16.h>

#define NSP 4096
#define BEPS 1e-5f
#define JSPLIT 4
#define JCHUNK (NSP / JSPLIT)

using short8  = __attribute__((ext_vector_type(8))) short;
using f32x4   = __attribute__((ext_vector_type(4))) float;

// scale * log2(e) : softmax exp(s*scale) == exp2(s*SCALE_LOG2E)
#define SCALE_LOG2E 0.25500526940103816f

__device__ __forceinline__ float b2f(unsigned short u) {
  return __uint_as_float(((unsigned)u) << 16);
}
__device__ __forceinline__ float b2f_lo(unsigned w) {
  return __uint_as_float(w << 16);
}
__device__ __forceinline__ float b2f_hi(unsigned w) {
  return __uint_as_float(w & 0xffff0000u);
}
// float -> bf16 bits, round-nearest-even (manual; non-hot paths)
__device__ __forceinline__ unsigned short f2b(float x) {
  unsigned u = __float_as_uint(x);
  u += 0x7fffu + ((u >> 16) & 1u);
  return (unsigned short)(u >> 16);
}
// HW packed convert: v_cvt_pk_bf16_f32 on gfx950 (1 inst vs ~10 manual)
__device__ __forceinline__ unsigned pk2u(float a, float b) {
  __hip_bfloat162 h = __float22bfloat162_rn(float2{a, b});
  unsigned r;
  __builtin_memcpy(&r, &h, sizeof(r));
  return r;
}

// ---------------- Kernel 0: transpose-cast x -> xT (b, n, c) bf16 ----------------
__global__ __launch_bounds__(256) void transpose_x_kernel(
    const float* __restrict__ x, unsigned short* __restrict__ xT)
{
  const int n0 = blockIdx.x * 64, c0 = blockIdx.y * 64, b = blockIdx.z;
  __shared__ __align__(16) unsigned short tx[64][72];   // [n][c]
  const int t = threadIdx.x;
  const int row = t >> 2;        // c index within tile
  const int seg = t & 3;         // 16 n each
  {
    const float* xp = x + ((size_t)(b * 256 + c0 + row)) * NSP + n0 + seg * 16;
    #pragma unroll
    for (int q4 = 0; q4 < 4; ++q4) {
      const float4 a = *reinterpret_cast<const float4*>(xp + q4 * 4);
      tx[seg * 16 + q4 * 4 + 0][row] = f2b(a.x);
      tx[seg * 16 + q4 * 4 + 1][row] = f2b(a.y);
      tx[seg * 16 + q4 * 4 + 2][row] = f2b(a.z);
      tx[seg * 16 + q4 * 4 + 3][row] = f2b(a.w);
    }
  }
  __syncthreads();
  const int nrow = t >> 2, ch = t & 3;
  unsigned short* op = xT + ((size_t)(b * NSP + n0 + nrow)) * 256 + c0 + ch * 16;
  *reinterpret_cast<float4*>(op)     = *reinterpret_cast<const float4*>(&tx[nrow][ch * 16]);
  *reinterpret_cast<float4*>(op + 8) = *reinterpret_cast<const float4*>(&tx[nrow][ch * 16 + 8]);
}

// ---------------- Kernel 1: MFMA qkv GEMM + BN + scatter (128-n tiles) ----------------
// W staged directly from fp32 with inline v_cvt_pk_bf16_f32 (no prep kernel).
// q rows: BN scale/bias pre-multiplied by SCALE_LOG2E so attn's softmax needs no mul.
__global__ __launch_bounds__(256) void qkv_gemm_kernel(
    const unsigned short* __restrict__ xT, const float* __restrict__ qkv_w,
    const float* __restrict__ gg, const float* __restrict__ bb,
    const float* __restrict__ mm, const float* __restrict__ vv,
    unsigned short* __restrict__ qb, unsigned short* __restrict__ kb,
    unsigned short* __restrict__ vb)
{
  const int n0 = blockIdx.x * 128;
  const int cotile = blockIdx.y;           // 8 tiles of 64 co
  const int b = blockIdx.z;
  const int co0 = cotile * 64;
  const int t = threadIdx.x;
  __shared__ __align__(16) unsigned short wt[64][136];    // [co][k-chunk 128]
  __shared__ __align__(16) unsigned short xt[128][136];   // [n][k-chunk 128]
  const int lane = t & 63, wave = t >> 6;
  const int m16 = lane & 15, quad = lane >> 4;

  f32x4 acc[8] = {};
  for (int kc = 0; kc < 2; ++kc) {
    if (kc) __syncthreads();
    {
      const float* wp = qkv_w + (size_t)(co0 + (t >> 2)) * 256 + kc * 128 + (t & 3) * 32;
      #pragma unroll
      for (int u = 0; u < 4; ++u) {
        const float4 a = *reinterpret_cast<const float4*>(wp + u * 8);
        const float4 c = *reinterpret_cast<const float4*>(wp + u * 8 + 4);
        uint4 w4;
        w4.x = pk2u(a.x, a.y); w4.y = pk2u(a.z, a.w);
        w4.z = pk2u(c.x, c.y); w4.w = pk2u(c.z, c.w);
        *reinterpret_cast<uint4*>(&wt[t >> 2][(t & 3) * 32 + u * 8]) = w4;
      }
      const unsigned short* xp = xT + ((size_t)(b * NSP + n0 + (t >> 1))) * 256 + kc * 128 + (t & 1) * 64;
      #pragma unroll
      for (int u = 0; u < 8; ++u)
        *reinterpret_cast<float4*>(&xt[t >> 1][(t & 1) * 64 + u * 8]) =
            *reinterpret_cast<const float4*>(xp + u * 8);
    }
    __syncthreads();
    if ((cotile & 1) == 0) {   // q/k: A = W (m=co), B = X (n=spatial)
      #pragma unroll
      for (int ks = 0; ks < 4; ++ks) {
        const short8 af = *reinterpret_cast<const short8*>(&wt[wave * 16 + m16][ks * 32 + quad * 8]);
        #pragma unroll
        for (int nt = 0; nt < 8; ++nt) {
          const short8 bf = *reinterpret_cast<const short8*>(&xt[nt * 16 + m16][ks * 32 + quad * 8]);
          acc[nt] = __builtin_amdgcn_mfma_f32_16x16x32_bf16(af, bf, acc[nt], 0, 0, 0);
        }
      }
    } else {                   // v: swapped -> A = X (m=spatial), B = W (n=co)
      #pragma unroll
      for (int ks = 0; ks < 4; ++ks) {
        const short8 bf = *reinterpret_cast<const short8*>(&wt[wave * 16 + m16][ks * 32 + quad * 8]);
        #pragma unroll
        for (int nt = 0; nt < 8; ++nt) {
          const short8 af = *reinterpret_cast<const short8*>(&xt[nt * 16 + m16][ks * 32 + quad * 8]);
          acc[nt] = __builtin_amdgcn_mfma_f32_16x16x32_bf16(af, bf, acc[nt], 0, 0, 0);
        }
      }
    }
  }

  const int head = cotile >> 1;
  const int bh = b * 4 + head;
  if ((cotile & 1) == 0) {
    const int coh = wave * 16 + quad * 4;   // 0..63 within head half (q if <32 else k)
    const bool isq = (coh < 32);
    const float fold = isq ? SCALE_LOG2E : 1.0f;   // pre-scale q for softmax exp2
    float sc[4], bi[4];
    #pragma unroll
    for (int r = 0; r < 4; ++r) {
      const int c = co0 + coh + r;
      const float s0 = gg[c] * rsqrtf(vv[c] + BEPS);
      sc[r] = s0 * fold;
      bi[r] = (bb[c] - mm[c] * s0) * fold;
    }
    unsigned short* dst = isq ? qb : kb;
    const int d0 = coh & 31;
    #pragma unroll
    for (int nt = 0; nt < 8; ++nt) {
      const int i = n0 + nt * 16 + m16;
      uint2 pk2;
      pk2.x = pk2u(acc[nt][0] * sc[0] + bi[0], acc[nt][1] * sc[1] + bi[1]);
      pk2.y = pk2u(acc[nt][2] * sc[2] + bi[2], acc[nt][3] * sc[3] + bi[3]);
      *reinterpret_cast<uint2*>(dst + ((size_t)bh * NSP + i) * 32 + d0) = pk2;
    }
  } else {
    const int c = co0 + wave * 16 + m16;
    const float sc = gg[c] * rsqrtf(vv[c] + BEPS);
    const float bi = bb[c] - mm[c] * sc;
    const int d = wave * 16 + m16;
    #pragma unroll
    for (int nt = 0; nt < 8; ++nt) {
      const int j = n0 + nt * 16 + quad * 4;
      uint2 pk2;
      pk2.x = pk2u(acc[nt][0] * sc + bi, acc[nt][1] * sc + bi);
      pk2.y = pk2u(acc[nt][2] * sc + bi, acc[nt][3] * sc + bi);
      *reinterpret_cast<uint2*>(vb + ((size_t)(bh * 64 + d)) * NSP + j) = pk2;
    }
  }
}

// ---------------- Kernel 2: MFMA flash attention (r13 structure) ----------------------
// 128-i tiles, reg-prefetch dbuf, Q pre-scaled, HW packed converts, ps LDS round-trip.
// Plain __launch_bounds__(256): no VGPR cap (r8/r16 lesson: min-waves arg caps the
// allocator and spills). Natural alloc ~64 VGPR; LDS 32KB permits up to 5 blocks/CU.
__global__ __launch_bounds__(256) void attn_kernel(
    const unsigned short* __restrict__ qb, const unsigned short* __restrict__ kb,
    const unsigned short* __restrict__ vb,
    unsigned short* __restrict__ Opart, float* __restrict__ lpart)
{
  const int i0    = blockIdx.x * 128;
  const int bh    = blockIdx.y;
  const int split = blockIdx.z;
  const int jbase = split * JCHUNK;
  const int t  = threadIdx.x;
  const int lane = t & 63, wave = t >> 6;
  const int m16 = lane & 15, quad = lane >> 4;
  __shared__ __align__(16) short smem[16384];       // 32 KB
  short (*qs)[40] = (short(*)[40])smem;             // [i][d]  128x40 (first 10.2KB)
  short (*ps)[72] = (short(*)[72])smem;             // [i][j]  128x72 (overlays qs, 18KB)
  short (*ks)[40] = (short(*)[40])(smem + 9216);    // [j][d]  64x40
  short (*vs)[72] = (short(*)[72])(smem + 9216 + 2560);  // [d][j] 64x72

  {  // stage Q once: 128 rows x 32 bf16 (each thread 32B)
    const unsigned short* qp = qb + ((size_t)bh * NSP + i0) * 32;
    const int r = t >> 1, h = t & 1;
    *reinterpret_cast<float4*>(&qs[r][h * 16]) =
        *reinterpret_cast<const float4*>(qp + r * 32 + h * 16);
    *reinterpret_cast<float4*>(&qs[r][h * 16 + 8]) =
        *reinterpret_cast<const float4*>(qp + r * 32 + h * 16 + 8);
  }
  __syncthreads();
  short8 qfrag[2];
  qfrag[0] = *reinterpret_cast<const short8*>(&qs[wave * 32 + m16][quad * 8]);
  qfrag[1] = *reinterpret_cast<const short8*>(&qs[wave * 32 + 16 + m16][quad * 8]);

  float rsum[2] = {0.f, 0.f};
  f32x4 oacc[2][4] = {};

  const int srow = t >> 2, schunk = t & 3;
  const unsigned short* kbase = kb + (size_t)bh * NSP * 32;
  const unsigned short* vbase = vb + (size_t)bh * 64 * NSP;

  // prologue: tile 0 -> regs -> LDS
  float4 kreg, vreg0, vreg1;
  kreg  = *reinterpret_cast<const float4*>(kbase + (size_t)(jbase + srow) * 32 + schunk * 8);
  vreg0 = *reinterpret_cast<const float4*>(vbase + (size_t)srow * NSP + jbase + schunk * 16);
  vreg1 = *reinterpret_cast<const float4*>(vbase + (size_t)srow * NSP + jbase + schunk * 16 + 8);
  *reinterpret_cast<float4*>(&ks[srow][schunk * 8]) = kreg;
  *reinterpret_cast<float4*>(&vs[srow][schunk * 16]) = vreg0;
  *reinterpret_cast<float4*>(&vs[srow][schunk * 16 + 8]) = vreg1;
  __syncthreads();   // tile 0 visible; all waves past qfrag extraction (ps overlay safe)

  for (int jt0 = 0; jt0 < JCHUNK; jt0 += 64) {
    const bool more = (jt0 + 64) < JCHUNK;
    if (more) {   // prefetch tile j+1 into regs; latency overlaps compute below
      const int jn = jbase + jt0 + 64;
      kreg  = *reinterpret_cast<const float4*>(kbase + (size_t)(jn + srow) * 32 + schunk * 8);
      vreg0 = *reinterpret_cast<const float4*>(vbase + (size_t)srow * NSP + jn + schunk * 16);
      vreg1 = *reinterpret_cast<const float4*>(vbase + (size_t)srow * NSP + jn + schunk * 16 + 8);
    }

    // K fragments once, reused for both i-halves
    short8 kf[4];
    #pragma unroll
    for (int jt = 0; jt < 4; ++jt)
      kf[jt] = *reinterpret_cast<const short8*>(&ks[jt * 16 + m16][quad * 8]);

    #pragma unroll
    for (int it = 0; it < 2; ++it) {
      // S^T sub-tile: A = K (m=j), B = Q (n=i) -> lane holds i, rows j.
      f32x4 sacc[4];
      #pragma unroll
      for (int jt = 0; jt < 4; ++jt)
        sacc[jt] = __builtin_amdgcn_mfma_f32_16x16x32_bf16(kf[jt], qfrag[it],
                                                           (f32x4){0.f,0.f,0.f,0.f}, 0, 0, 0);
      const int irow = wave * 32 + it * 16 + m16;
      #pragma unroll
      for (int jt = 0; jt < 4; ++jt) {
        float p0 = __builtin_amdgcn_exp2f(sacc[jt][0]);
        float p1 = __builtin_amdgcn_exp2f(sacc[jt][1]);
        float p2 = __builtin_amdgcn_exp2f(sacc[jt][2]);
        float p3 = __builtin_amdgcn_exp2f(sacc[jt][3]);
        rsum[it] += (p0 + p1) + (p2 + p3);
        uint2 pk2;
        pk2.x = pk2u(p0, p1);
        pk2.y = pk2u(p2, p3);
        *reinterpret_cast<uint2*>(&ps[irow][jt * 16 + quad * 4]) = pk2;
      }
    }

    // PV: O[i][d] += P[i][j] V[j][d]; V-frags reused for both i-halves.
    short8 pa[2][2];
    #pragma unroll
    for (int it = 0; it < 2; ++it) {
      pa[it][0] = *reinterpret_cast<const short8*>(&ps[wave * 32 + it * 16 + m16][quad * 8]);
      pa[it][1] = *reinterpret_cast<const short8*>(&ps[wave * 32 + it * 16 + m16][32 + quad * 8]);
    }
    #pragma unroll
    for (int dt = 0; dt < 4; ++dt) {
      const short8 v0 = *reinterpret_cast<const short8*>(&vs[dt * 16 + m16][quad * 8]);
      const short8 v1 = *reinterpret_cast<const short8*>(&vs[dt * 16 + m16][32 + quad * 8]);
      #pragma unroll
      for (int it = 0; it < 2; ++it) {
        oacc[it][dt] = __builtin_amdgcn_mfma_f32_16x16x32_bf16(pa[it][0], v0, oacc[it][dt], 0, 0, 0);
        oacc[it][dt] = __builtin_amdgcn_mfma_f32_16x16x32_bf16(pa[it][1], v1, oacc[it][dt], 0, 0, 0);
      }
    }

    if (more) {   // commit prefetched tile to LDS
      __syncthreads();   // all reads of ks/vs for tile j done
      *reinterpret_cast<float4*>(&ks[srow][schunk * 8]) = kreg;
      *reinterpret_cast<float4*>(&vs[srow][schunk * 16]) = vreg0;
      *reinterpret_cast<float4*>(&vs[srow][schunk * 16 + 8]) = vreg1;
      __syncthreads();   // tile j+1 visible
    }
  }

  // finalize l for this block's j-range: reduce across quads (same m16)
  #pragma unroll
  for (int it = 0; it < 2; ++it) {
    float rs = rsum[it];
    rs += __shfl_xor(rs, 16);
    rs += __shfl_xor(rs, 32);
    if (quad == 0)
      lpart[((size_t)split * 8 + bh) * NSP + i0 + wave * 32 + it * 16 + m16] = rs;
  }

  // store unnormalized O partial as bf16: [split][bh][d][i], 4 consecutive i -> 8B
  #pragma unroll
  for (int it = 0; it < 2; ++it)
    #pragma unroll
    for (int dt = 0; dt < 4; ++dt) {
      const int d = dt * 16 + m16;
      uint2 pk2;
      pk2.x = pk2u(oacc[it][dt][0], oacc[it][dt][1]);
      pk2.y = pk2u(oacc[it][dt][2], oacc[it][dt][3]);
      *reinterpret_cast<uint2*>(Opart +
          (((size_t)split * 8 + bh) * 64 + d) * NSP + i0 + wave * 32 + it * 16 + quad * 4) = pk2;
    }
}

// ---------------- Kernel 3: fused combine + pe -> yT (b, n, c) bf16 (vectorized) --------
__global__ __launch_bounds__(256) void fuse_kernel(
    const unsigned short* __restrict__ Opart, const float* __restrict__ lpart,
    const unsigned short* __restrict__ vb,
    const float* __restrict__ pw, const float* __restrict__ pg,
    const float* __restrict__ pb, const float* __restrict__ pm,
    const float* __restrict__ pv,
    unsigned short* __restrict__ yT)
{
  const int py = blockIdx.x;       // spatial row
  const int bh = blockIdx.y;       // 8
  const int b = bh >> 2, h = bh & 3;
  const int t = threadIdx.x;
  const int d = t >> 2, seg = t & 3;      // d 0..63 ; px window = seg*16..+15
  __shared__ float lsum[64];
  __shared__ __align__(16) unsigned short yt[64][72];   // [px][d]

  if (t < 64) {
    float ls = 0.f;
    #pragma unroll
    for (int s = 0; s < JSPLIT; ++s)
      ls += lpart[((size_t)s * 8 + bh) * NSP + py * 64 + t];
    lsum[t] = ls;
  }
  __syncthreads();

  const int c = h * 64 + d;
  const int i0 = py * 64 + seg * 16;
  float os[16] = {};
  #pragma unroll
  for (int s = 0; s < JSPLIT; ++s) {
    const uint4* op = reinterpret_cast<const uint4*>(
        Opart + (((size_t)s * 8 + bh) * 64 + d) * NSP + i0);
    const uint4 a = op[0], e = op[1];
    os[0]  += b2f_lo(a.x); os[1]  += b2f_hi(a.x);
    os[2]  += b2f_lo(a.y); os[3]  += b2f_hi(a.y);
    os[4]  += b2f_lo(a.z); os[5]  += b2f_hi(a.z);
    os[6]  += b2f_lo(a.w); os[7]  += b2f_hi(a.w);
    os[8]  += b2f_lo(e.x); os[9]  += b2f_hi(e.x);
    os[10] += b2f_lo(e.y); os[11] += b2f_hi(e.y);
    os[12] += b2f_lo(e.z); os[13] += b2f_hi(e.z);
    os[14] += b2f_lo(e.w); os[15] += b2f_hi(e.w);
  }

  float w9[9];
  #pragma unroll
  for (int i = 0; i < 9; ++i) w9[i] = pw[c * 9 + i];
  const float sc = pg[c] * rsqrtf(pv[c] + BEPS);
  const float bi = pb[c] - pm[c] * sc;
  const unsigned short* vrow = vb + ((size_t)(bh * 64 + d)) * NSP;

  float conv[16] = {};
  #pragma unroll
  for (int dy = -1; dy <= 1; ++dy) {
    const int yy = py + dy;
    if (yy < 0 || yy > 63) continue;
    const unsigned short* vr = vrow + yy * 64 + seg * 16;
    float vals[18];
    const uint4 m0 = *reinterpret_cast<const uint4*>(vr);
    const uint4 m1 = *reinterpret_cast<const uint4*>(vr + 8);
    vals[1]  = b2f_lo(m0.x); vals[2]  = b2f_hi(m0.x);
    vals[3]  = b2f_lo(m0.y); vals[4]  = b2f_hi(m0.y);
    vals[5]  = b2f_lo(m0.z); vals[6]  = b2f_hi(m0.z);
    vals[7]  = b2f_lo(m0.w); vals[8]  = b2f_hi(m0.w);
    vals[9]  = b2f_lo(m1.x); vals[10] = b2f_hi(m1.x);
    vals[11] = b2f_lo(m1.y); vals[12] = b2f_hi(m1.y);
    vals[13] = b2f_lo(m1.z); vals[14] = b2f_hi(m1.z);
    vals[15] = b2f_lo(m1.w); vals[16] = b2f_hi(m1.w);
    vals[0]  = (seg > 0) ? b2f_hi(*reinterpret_cast<const unsigned*>(vr - 2)) : 0.f;
    vals[17] = (seg < 3) ? b2f_lo(*reinterpret_cast<const unsigned*>(vr + 16)) : 0.f;
    const float wr0 = w9[(dy + 1) * 3 + 0], wr1 = w9[(dy + 1) * 3 + 1], wr2 = w9[(dy + 1) * 3 + 2];
    #pragma unroll
    for (int u = 0; u < 16; ++u)
      conv[u] += vals[u] * wr0 + vals[u + 1] * wr1 + vals[u + 2] * wr2;
  }

  #pragma unroll
  for (int u = 0; u < 16; ++u) {
    const float yv = os[u] / lsum[seg * 16 + u] + conv[u] * sc + bi;
    yt[seg * 16 + u][d] = f2b(yv);
  }
  __syncthreads();

  const int prow = t >> 2, ch = t & 3;
  unsigned short* op = yT + ((size_t)(b * NSP + py * 64 + prow)) * 256 + h * 64 + ch * 16;
  *reinterpret_cast<float4*>(op)     = *reinterpret_cast<const float4*>(&yt[prow][ch * 16]);
  *reinterpret_cast<float4*>(op + 8) = *reinterpret_cast<const float4*>(&yt[prow][ch * 16 + 8]);
}

// ---------------- Kernel 4: MFMA proj GEMM + BN -> out f32 (128-n tiles) ----------------
// W staged directly from fp32 with inline v_cvt_pk_bf16_f32 (no prep kernel).
__global__ __launch_bounds__(256) void proj_gemm_kernel(
    const unsigned short* __restrict__ yT, const float* __restrict__ proj_w,
    const float* __restrict__ gg, const float* __restrict__ bb,
    const float* __restrict__ mm, const float* __restrict__ vv,
    float* __restrict__ out)
{
  const int n0 = blockIdx.x * 128;
  const int co0 = blockIdx.y * 64;   // 4 tiles
  const int b = blockIdx.z;
  const int t = threadIdx.x;
  __shared__ __align__(16) unsigned short wt[64][136];
  __shared__ __align__(16) unsigned short yt[128][136];
  const int lane = t & 63, wave = t >> 6;
  const int m16 = lane & 15, quad = lane >> 4;

  f32x4 acc[8] = {};
  for (int kc = 0; kc < 2; ++kc) {
    if (kc) __syncthreads();
    {
      const float* wp = proj_w + (size_t)(co0 + (t >> 2)) * 256 + kc * 128 + (t & 3) * 32;
      #pragma unroll
      for (int u = 0; u < 4; ++u) {
        const float4 a = *reinterpret_cast<const float4*>(wp + u * 8);
        const float4 c = *reinterpret_cast<const float4*>(wp + u * 8 + 4);
        uint4 w4;
        w4.x = pk2u(a.x, a.y); w4.y = pk2u(a.z, a.w);
        w4.z = pk2u(c.x, c.y); w4.w = pk2u(c.z, c.w);
        *reinterpret_cast<uint4*>(&wt[t >> 2][(t & 3) * 32 + u * 8]) = w4;
      }
      const unsigned short* yp = yT + ((size_t)(b * NSP + n0 + (t >> 1))) * 256 + kc * 128 + (t & 1) * 64;
      #pragma unroll
      for (int u = 0; u < 8; ++u)
        *reinterpret_cast<float4*>(&yt[t >> 1][(t & 1) * 64 + u * 8]) =
            *reinterpret_cast<const float4*>(yp + u * 8);
    }
    __syncthreads();
    #pragma unroll
    for (int ks = 0; ks < 4; ++ks) {
      const short8 bf = *reinterpret_cast<const short8*>(&wt[wave * 16 + m16][ks * 32 + quad * 8]);
      #pragma unroll
      for (int nt = 0; nt < 8; ++nt) {
        const short8 af = *reinterpret_cast<const short8*>(&yt[nt * 16 + m16][ks * 32 + quad * 8]);
        acc[nt] = __builtin_amdgcn_mfma_f32_16x16x32_bf16(af, bf, acc[nt], 0, 0, 0);
      }
    }
  }

  const int c = co0 + wave * 16 + m16;
  const float sc = gg[c] * rsqrtf(vv[c] + BEPS);
  const float bi = bb[c] - mm[c] * sc;
  #pragma unroll
  for (int nt = 0; nt < 8; ++nt) {
    const int n = n0 + nt * 16 + quad * 4;
    float4 ov;
    ov.x = acc[nt][0] * sc + bi; ov.y = acc[nt][1] * sc + bi;
    ov.z = acc[nt][2] * sc + bi; ov.w = acc[nt][3] * sc + bi;
    *reinterpret_cast<float4*>(out + ((size_t)(b * 256 + c)) * NSP + n) = ov;
  }
}

extern "C" void kernel_launch(void* const* d_in, const int* in_sizes, int n_in,
                              void* d_out, int out_size, void* d_ws, size_t ws_size,
                              hipStream_t stream)
{
  const float* x      = (const float*)d_in[0];
  const float* qkv_w  = (const float*)d_in[1];
  const float* qkv_g  = (const float*)d_in[2];
  const float* qkv_b  = (const float*)d_in[3];
  const float* qkv_m  = (const float*)d_in[4];
  const float* qkv_v  = (const float*)d_in[5];
  const float* proj_w = (const float*)d_in[6];
  const float* proj_g = (const float*)d_in[7];
  const float* proj_b = (const float*)d_in[8];
  const float* proj_m = (const float*)d_in[9];
  const float* proj_v = (const float*)d_in[10];
  const float* pe_w   = (const float*)d_in[11];
  const float* pe_g   = (const float*)d_in[12];
  const float* pe_b   = (const float*)d_in[13];
  const float* pe_m   = (const float*)d_in[14];
  const float* pe_v   = (const float*)d_in[15];
  float* out = (float*)d_out;

  unsigned short* qb = (unsigned short*)d_ws;             // 2MB
  unsigned short* kb = qb + (size_t)8 * NSP * 32;         // 2MB
  unsigned short* vb = kb + (size_t)8 * NSP * 32;         // 4MB
  unsigned short* Opart = vb + (size_t)8 * 64 * NSP;      // 16MB
  float* lpart = (float*)(Opart + (size_t)JSPLIT * 8 * 64 * NSP);  // 512KB
  unsigned short* xT = (unsigned short*)(lpart + (size_t)JSPLIT * 8 * NSP);  // 4MB
  unsigned short* yT = xT + (size_t)2 * NSP * 256;        // 4MB

  transpose_x_kernel<<<dim3(64, 4, 2), 256, 0, stream>>>(x, xT);
  qkv_gemm_kernel<<<dim3(32, 8, 2), 256, 0, stream>>>(xT, qkv_w, qkv_g, qkv_b, qkv_m, qkv_v,
                                                      qb, kb, vb);
  attn_kernel<<<dim3(32, 8, JSPLIT), 256, 0, stream>>>(qb, kb, vb, Opart, lpart);
  fuse_kernel<<<dim3(64, 8), 256, 0, stream>>>(Opart, lpart, vb,
                                               pe_w, pe_g, pe_b, pe_m, pe_v, yT);
  proj_gemm_kernel<<<dim3(32, 4, 2), 256, 0, stream>>>(yT, proj_w, proj_g, proj_b, proj_m, proj_v,
                                                       out);
}

// Round 18
// 156.533 us; speedup vs baseline: 1.4760x; 1.0627x over previous
//
#include <hip/hip_runtime.h>
#include <hip/hip_bf16.h>

#define NSP 4096
#define BEPS 1e-5f
#define JSPLIT 4
#define JCHUNK (NSP / JSPLIT)

using short8  = __attribute__((ext_vector_type(8))) short;
using f32x4   = __attribute__((ext_vector_type(4))) float;

// scale * log2(e) : softmax exp(s*scale) == exp2(s*SCALE_LOG2E)
#define SCALE_LOG2E 0.25500526940103816f

__device__ __forceinline__ float b2f(unsigned short u) {
  return __uint_as_float(((unsigned)u) << 16);
}
__device__ __forceinline__ float b2f_lo(unsigned w) {
  return __uint_as_float(w << 16);
}
__device__ __forceinline__ float b2f_hi(unsigned w) {
  return __uint_as_float(w & 0xffff0000u);
}
// float -> bf16 bits, round-nearest-even (manual; non-hot paths)
__device__ __forceinline__ unsigned short f2b(float x) {
  unsigned u = __float_as_uint(x);
  u += 0x7fffu + ((u >> 16) & 1u);
  return (unsigned short)(u >> 16);
}
__device__ __forceinline__ unsigned pk_bf16(float a, float b) {
  return ((unsigned)f2b(b) << 16) | (unsigned)f2b(a);
}
// HW packed convert: v_cvt_pk_bf16_f32 on gfx950 (1 inst vs ~10 manual)
__device__ __forceinline__ unsigned pk2u(float a, float b) {
  __hip_bfloat162 h = __float22bfloat162_rn(float2{a, b});
  unsigned r;
  __builtin_memcpy(&r, &h, sizeof(r));
  return r;
}

// ---------------- Kernel 0a: cast weights to bf16 ----------------
__global__ __launch_bounds__(256) void cast_w_kernel(
    const float* __restrict__ qkv_w, const float* __restrict__ proj_w,
    unsigned short* __restrict__ wqb, unsigned short* __restrict__ wpb)
{
  const int i = blockIdx.x * 256 + threadIdx.x;   // grid 768 -> 196608 threads
  if (i < 131072)       wqb[i] = f2b(qkv_w[i]);
  else                  wpb[i - 131072] = f2b(proj_w[i - 131072]);
}

// ---------------- Kernel 0b: transpose-cast x -> xT (b, n, c) bf16 ----------------
__global__ __launch_bounds__(256) void transpose_x_kernel(
    const float* __restrict__ x, unsigned short* __restrict__ xT)
{
  const int n0 = blockIdx.x * 64, c0 = blockIdx.y * 64, b = blockIdx.z;
  __shared__ __align__(16) unsigned short tx[64][72];   // [n][c]
  const int t = threadIdx.x;
  const int row = t >> 2;        // c index within tile
  const int seg = t & 3;         // 16 n each
  {
    const float* xp = x + ((size_t)(b * 256 + c0 + row)) * NSP + n0 + seg * 16;
    #pragma unroll
    for (int q4 = 0; q4 < 4; ++q4) {
      const float4 a = *reinterpret_cast<const float4*>(xp + q4 * 4);
      tx[seg * 16 + q4 * 4 + 0][row] = f2b(a.x);
      tx[seg * 16 + q4 * 4 + 1][row] = f2b(a.y);
      tx[seg * 16 + q4 * 4 + 2][row] = f2b(a.z);
      tx[seg * 16 + q4 * 4 + 3][row] = f2b(a.w);
    }
  }
  __syncthreads();
  const int nrow = t >> 2, ch = t & 3;
  unsigned short* op = xT + ((size_t)(b * NSP + n0 + nrow)) * 256 + c0 + ch * 16;
  *reinterpret_cast<float4*>(op)     = *reinterpret_cast<const float4*>(&tx[nrow][ch * 16]);
  *reinterpret_cast<float4*>(op + 8) = *reinterpret_cast<const float4*>(&tx[nrow][ch * 16 + 8]);
}

// ---------------- Kernel 1: MFMA qkv GEMM + BN + scatter (128-n tiles) ----------------
// q rows: BN scale/bias pre-multiplied by SCALE_LOG2E so attn's softmax needs no mul.
__global__ __launch_bounds__(256) void qkv_gemm_kernel(
    const unsigned short* __restrict__ xT, const unsigned short* __restrict__ wqb,
    const float* __restrict__ gg, const float* __restrict__ bb,
    const float* __restrict__ mm, const float* __restrict__ vv,
    unsigned short* __restrict__ qb, unsigned short* __restrict__ kb,
    unsigned short* __restrict__ vb)
{
  const int n0 = blockIdx.x * 128;
  const int cotile = blockIdx.y;           // 8 tiles of 64 co
  const int b = blockIdx.z;
  const int co0 = cotile * 64;
  const int t = threadIdx.x;
  __shared__ __align__(16) unsigned short wt[64][136];    // [co][k-chunk 128]
  __shared__ __align__(16) unsigned short xt[128][136];   // [n][k-chunk 128]
  const int lane = t & 63, wave = t >> 6;
  const int m16 = lane & 15, quad = lane >> 4;

  f32x4 acc[8] = {};
  for (int kc = 0; kc < 2; ++kc) {
    if (kc) __syncthreads();
    {
      const unsigned short* wp = wqb + (size_t)(co0 + (t >> 2)) * 256 + kc * 128 + (t & 3) * 32;
      #pragma unroll
      for (int u = 0; u < 4; ++u)
        *reinterpret_cast<float4*>(&wt[t >> 2][(t & 3) * 32 + u * 8]) =
            *reinterpret_cast<const float4*>(wp + u * 8);
      const unsigned short* xp = xT + ((size_t)(b * NSP + n0 + (t >> 1))) * 256 + kc * 128 + (t & 1) * 64;
      #pragma unroll
      for (int u = 0; u < 8; ++u)
        *reinterpret_cast<float4*>(&xt[t >> 1][(t & 1) * 64 + u * 8]) =
            *reinterpret_cast<const float4*>(xp + u * 8);
    }
    __syncthreads();
    if ((cotile & 1) == 0) {   // q/k: A = W (m=co), B = X (n=spatial)
      #pragma unroll
      for (int ks = 0; ks < 4; ++ks) {
        const short8 af = *reinterpret_cast<const short8*>(&wt[wave * 16 + m16][ks * 32 + quad * 8]);
        #pragma unroll
        for (int nt = 0; nt < 8; ++nt) {
          const short8 bf = *reinterpret_cast<const short8*>(&xt[nt * 16 + m16][ks * 32 + quad * 8]);
          acc[nt] = __builtin_amdgcn_mfma_f32_16x16x32_bf16(af, bf, acc[nt], 0, 0, 0);
        }
      }
    } else {                   // v: swapped -> A = X (m=spatial), B = W (n=co)
      #pragma unroll
      for (int ks = 0; ks < 4; ++ks) {
        const short8 bf = *reinterpret_cast<const short8*>(&wt[wave * 16 + m16][ks * 32 + quad * 8]);
        #pragma unroll
        for (int nt = 0; nt < 8; ++nt) {
          const short8 af = *reinterpret_cast<const short8*>(&xt[nt * 16 + m16][ks * 32 + quad * 8]);
          acc[nt] = __builtin_amdgcn_mfma_f32_16x16x32_bf16(af, bf, acc[nt], 0, 0, 0);
        }
      }
    }
  }

  const int head = cotile >> 1;
  const int bh = b * 4 + head;
  if ((cotile & 1) == 0) {
    const int coh = wave * 16 + quad * 4;   // 0..63 within head half (q if <32 else k)
    const bool isq = (coh < 32);
    const float fold = isq ? SCALE_LOG2E : 1.0f;   // pre-scale q for softmax exp2
    float sc[4], bi[4];
    #pragma unroll
    for (int r = 0; r < 4; ++r) {
      const int c = co0 + coh + r;
      const float s0 = gg[c] * rsqrtf(vv[c] + BEPS);
      sc[r] = s0 * fold;
      bi[r] = (bb[c] - mm[c] * s0) * fold;
    }
    unsigned short* dst = isq ? qb : kb;
    const int d0 = coh & 31;
    #pragma unroll
    for (int nt = 0; nt < 8; ++nt) {
      const int i = n0 + nt * 16 + m16;
      uint2 pk2;
      pk2.x = pk_bf16(acc[nt][0] * sc[0] + bi[0], acc[nt][1] * sc[1] + bi[1]);
      pk2.y = pk_bf16(acc[nt][2] * sc[2] + bi[2], acc[nt][3] * sc[3] + bi[3]);
      *reinterpret_cast<uint2*>(dst + ((size_t)bh * NSP + i) * 32 + d0) = pk2;
    }
  } else {
    const int c = co0 + wave * 16 + m16;
    const float sc = gg[c] * rsqrtf(vv[c] + BEPS);
    const float bi = bb[c] - mm[c] * sc;
    const int d = wave * 16 + m16;
    #pragma unroll
    for (int nt = 0; nt < 8; ++nt) {
      const int j = n0 + nt * 16 + quad * 4;
      uint2 pk2;
      pk2.x = pk_bf16(acc[nt][0] * sc + bi, acc[nt][1] * sc + bi);
      pk2.y = pk_bf16(acc[nt][2] * sc + bi, acc[nt][3] * sc + bi);
      *reinterpret_cast<uint2*>(vb + ((size_t)(bh * 64 + d)) * NSP + j) = pk2;
    }
  }
}

// ---------------- Kernel 2: MFMA flash attention, 128-i tiles, reg-prefetch dbuf --------
// Q pre-scaled by scale*log2e (qkv epilogue) -> softmax is exp2(s) directly.
// HW packed bf16 converts (v_cvt_pk_bf16_f32) on P-write and O-store paths.
// (256,4): measured local optimum — 64 VGPR, no spill (r8/r16: (256,5) spills;
// r17: unbounded takes 80 VGPR and loses occupancy).
__global__ __launch_bounds__(256, 4) void attn_kernel(
    const unsigned short* __restrict__ qb, const unsigned short* __restrict__ kb,
    const unsigned short* __restrict__ vb,
    unsigned short* __restrict__ Opart, float* __restrict__ lpart)
{
  const int i0    = blockIdx.x * 128;
  const int bh    = blockIdx.y;
  const int split = blockIdx.z;
  const int jbase = split * JCHUNK;
  const int t  = threadIdx.x;
  const int lane = t & 63, wave = t >> 6;
  const int m16 = lane & 15, quad = lane >> 4;
  __shared__ __align__(16) short smem[16384];       // 32 KB
  short (*qs)[40] = (short(*)[40])smem;             // [i][d]  128x40 (first 10.2KB)
  short (*ps)[72] = (short(*)[72])smem;             // [i][j]  128x72 (overlays qs, 18KB)
  short (*ks)[40] = (short(*)[40])(smem + 9216);    // [j][d]  64x40
  short (*vs)[72] = (short(*)[72])(smem + 9216 + 2560);  // [d][j] 64x72

  {  // stage Q once: 128 rows x 32 bf16 (each thread 32B)
    const unsigned short* qp = qb + ((size_t)bh * NSP + i0) * 32;
    const int r = t >> 1, h = t & 1;
    *reinterpret_cast<float4*>(&qs[r][h * 16]) =
        *reinterpret_cast<const float4*>(qp + r * 32 + h * 16);
    *reinterpret_cast<float4*>(&qs[r][h * 16 + 8]) =
        *reinterpret_cast<const float4*>(qp + r * 32 + h * 16 + 8);
  }
  __syncthreads();
  short8 qfrag[2];
  qfrag[0] = *reinterpret_cast<const short8*>(&qs[wave * 32 + m16][quad * 8]);
  qfrag[1] = *reinterpret_cast<const short8*>(&qs[wave * 32 + 16 + m16][quad * 8]);

  float rsum[2] = {0.f, 0.f};
  f32x4 oacc[2][4] = {};

  const int srow = t >> 2, schunk = t & 3;
  const unsigned short* kbase = kb + (size_t)bh * NSP * 32;
  const unsigned short* vbase = vb + (size_t)bh * 64 * NSP;

  // prologue: tile 0 -> regs -> LDS
  float4 kreg, vreg0, vreg1;
  kreg  = *reinterpret_cast<const float4*>(kbase + (size_t)(jbase + srow) * 32 + schunk * 8);
  vreg0 = *reinterpret_cast<const float4*>(vbase + (size_t)srow * NSP + jbase + schunk * 16);
  vreg1 = *reinterpret_cast<const float4*>(vbase + (size_t)srow * NSP + jbase + schunk * 16 + 8);
  *reinterpret_cast<float4*>(&ks[srow][schunk * 8]) = kreg;
  *reinterpret_cast<float4*>(&vs[srow][schunk * 16]) = vreg0;
  *reinterpret_cast<float4*>(&vs[srow][schunk * 16 + 8]) = vreg1;
  __syncthreads();   // tile 0 visible; all waves past qfrag extraction (ps overlay safe)

  for (int jt0 = 0; jt0 < JCHUNK; jt0 += 64) {
    const bool more = (jt0 + 64) < JCHUNK;
    if (more) {   // prefetch tile j+1 into regs; latency overlaps compute below
      const int jn = jbase + jt0 + 64;
      kreg  = *reinterpret_cast<const float4*>(kbase + (size_t)(jn + srow) * 32 + schunk * 8);
      vreg0 = *reinterpret_cast<const float4*>(vbase + (size_t)srow * NSP + jn + schunk * 16);
      vreg1 = *reinterpret_cast<const float4*>(vbase + (size_t)srow * NSP + jn + schunk * 16 + 8);
    }

    // K fragments once, reused for both i-halves
    short8 kf[4];
    #pragma unroll
    for (int jt = 0; jt < 4; ++jt)
      kf[jt] = *reinterpret_cast<const short8*>(&ks[jt * 16 + m16][quad * 8]);

    #pragma unroll
    for (int it = 0; it < 2; ++it) {
      // S^T sub-tile: A = K (m=j), B = Q (n=i) -> lane holds i, rows j.
      f32x4 sacc[4];
      #pragma unroll
      for (int jt = 0; jt < 4; ++jt)
        sacc[jt] = __builtin_amdgcn_mfma_f32_16x16x32_bf16(kf[jt], qfrag[it],
                                                           (f32x4){0.f,0.f,0.f,0.f}, 0, 0, 0);
      const int irow = wave * 32 + it * 16 + m16;
      #pragma unroll
      for (int jt = 0; jt < 4; ++jt) {
        float p0 = __builtin_amdgcn_exp2f(sacc[jt][0]);
        float p1 = __builtin_amdgcn_exp2f(sacc[jt][1]);
        float p2 = __builtin_amdgcn_exp2f(sacc[jt][2]);
        float p3 = __builtin_amdgcn_exp2f(sacc[jt][3]);
        rsum[it] += (p0 + p1) + (p2 + p3);
        uint2 pk2;
        pk2.x = pk2u(p0, p1);
        pk2.y = pk2u(p2, p3);
        *reinterpret_cast<uint2*>(&ps[irow][jt * 16 + quad * 4]) = pk2;
      }
    }

    // PV: O[i][d] += P[i][j] V[j][d]; V-frags reused for both i-halves.
    short8 pa[2][2];
    #pragma unroll
    for (int it = 0; it < 2; ++it) {
      pa[it][0] = *reinterpret_cast<const short8*>(&ps[wave * 32 + it * 16 + m16][quad * 8]);
      pa[it][1] = *reinterpret_cast<const short8*>(&ps[wave * 32 + it * 16 + m16][32 + quad * 8]);
    }
    #pragma unroll
    for (int dt = 0; dt < 4; ++dt) {
      const short8 v0 = *reinterpret_cast<const short8*>(&vs[dt * 16 + m16][quad * 8]);
      const short8 v1 = *reinterpret_cast<const short8*>(&vs[dt * 16 + m16][32 + quad * 8]);
      #pragma unroll
      for (int it = 0; it < 2; ++it) {
        oacc[it][dt] = __builtin_amdgcn_mfma_f32_16x16x32_bf16(pa[it][0], v0, oacc[it][dt], 0, 0, 0);
        oacc[it][dt] = __builtin_amdgcn_mfma_f32_16x16x32_bf16(pa[it][1], v1, oacc[it][dt], 0, 0, 0);
      }
    }

    if (more) {   // commit prefetched tile to LDS
      __syncthreads();   // all reads of ks/vs for tile j done
      *reinterpret_cast<float4*>(&ks[srow][schunk * 8]) = kreg;
      *reinterpret_cast<float4*>(&vs[srow][schunk * 16]) = vreg0;
      *reinterpret_cast<float4*>(&vs[srow][schunk * 16 + 8]) = vreg1;
      __syncthreads();   // tile j+1 visible
    }
  }

  // finalize l for this block's j-range: reduce across quads (same m16)
  #pragma unroll
  for (int it = 0; it < 2; ++it) {
    float rs = rsum[it];
    rs += __shfl_xor(rs, 16);
    rs += __shfl_xor(rs, 32);
    if (quad == 0)
      lpart[((size_t)split * 8 + bh) * NSP + i0 + wave * 32 + it * 16 + m16] = rs;
  }

  // store unnormalized O partial as bf16: [split][bh][d][i], 4 consecutive i -> 8B
  #pragma unroll
  for (int it = 0; it < 2; ++it)
    #pragma unroll
    for (int dt = 0; dt < 4; ++dt) {
      const int d = dt * 16 + m16;
      uint2 pk2;
      pk2.x = pk2u(oacc[it][dt][0], oacc[it][dt][1]);
      pk2.y = pk2u(oacc[it][dt][2], oacc[it][dt][3]);
      *reinterpret_cast<uint2*>(Opart +
          (((size_t)split * 8 + bh) * 64 + d) * NSP + i0 + wave * 32 + it * 16 + quad * 4) = pk2;
    }
}

// ---------------- Kernel 3: fused combine + pe -> yT (b, n, c) bf16 (vectorized) --------
__global__ __launch_bounds__(256) void fuse_kernel(
    const unsigned short* __restrict__ Opart, const float* __restrict__ lpart,
    const unsigned short* __restrict__ vb,
    const float* __restrict__ pw, const float* __restrict__ pg,
    const float* __restrict__ pb, const float* __restrict__ pm,
    const float* __restrict__ pv,
    unsigned short* __restrict__ yT)
{
  const int py = blockIdx.x;       // spatial row
  const int bh = blockIdx.y;       // 8
  const int b = bh >> 2, h = bh & 3;
  const int t = threadIdx.x;
  const int d = t >> 2, seg = t & 3;      // d 0..63 ; px window = seg*16..+15
  __shared__ float lsum[64];
  __shared__ __align__(16) unsigned short yt[64][72];   // [px][d]

  if (t < 64) {
    float ls = 0.f;
    #pragma unroll
    for (int s = 0; s < JSPLIT; ++s)
      ls += lpart[((size_t)s * 8 + bh) * NSP + py * 64 + t];
    lsum[t] = ls;
  }
  __syncthreads();

  const int c = h * 64 + d;
  const int i0 = py * 64 + seg * 16;
  float os[16] = {};
  #pragma unroll
  for (int s = 0; s < JSPLIT; ++s) {
    const uint4* op = reinterpret_cast<const uint4*>(
        Opart + (((size_t)s * 8 + bh) * 64 + d) * NSP + i0);
    const uint4 a = op[0], e = op[1];
    os[0]  += b2f_lo(a.x); os[1]  += b2f_hi(a.x);
    os[2]  += b2f_lo(a.y); os[3]  += b2f_hi(a.y);
    os[4]  += b2f_lo(a.z); os[5]  += b2f_hi(a.z);
    os[6]  += b2f_lo(a.w); os[7]  += b2f_hi(a.w);
    os[8]  += b2f_lo(e.x); os[9]  += b2f_hi(e.x);
    os[10] += b2f_lo(e.y); os[11] += b2f_hi(e.y);
    os[12] += b2f_lo(e.z); os[13] += b2f_hi(e.z);
    os[14] += b2f_lo(e.w); os[15] += b2f_hi(e.w);
  }

  float w9[9];
  #pragma unroll
  for (int i = 0; i < 9; ++i) w9[i] = pw[c * 9 + i];
  const float sc = pg[c] * rsqrtf(pv[c] + BEPS);
  const float bi = pb[c] - pm[c] * sc;
  const unsigned short* vrow = vb + ((size_t)(bh * 64 + d)) * NSP;

  float conv[16] = {};
  #pragma unroll
  for (int dy = -1; dy <= 1; ++dy) {
    const int yy = py + dy;
    if (yy < 0 || yy > 63) continue;
    const unsigned short* vr = vrow + yy * 64 + seg * 16;
    float vals[18];
    const uint4 m0 = *reinterpret_cast<const uint4*>(vr);
    const uint4 m1 = *reinterpret_cast<const uint4*>(vr + 8);
    vals[1]  = b2f_lo(m0.x); vals[2]  = b2f_hi(m0.x);
    vals[3]  = b2f_lo(m0.y); vals[4]  = b2f_hi(m0.y);
    vals[5]  = b2f_lo(m0.z); vals[6]  = b2f_hi(m0.z);
    vals[7]  = b2f_lo(m0.w); vals[8]  = b2f_hi(m0.w);
    vals[9]  = b2f_lo(m1.x); vals[10] = b2f_hi(m1.x);
    vals[11] = b2f_lo(m1.y); vals[12] = b2f_hi(m1.y);
    vals[13] = b2f_lo(m1.z); vals[14] = b2f_hi(m1.z);
    vals[15] = b2f_lo(m1.w); vals[16] = b2f_hi(m1.w);
    vals[0]  = (seg > 0) ? b2f_hi(*reinterpret_cast<const unsigned*>(vr - 2)) : 0.f;
    vals[17] = (seg < 3) ? b2f_lo(*reinterpret_cast<const unsigned*>(vr + 16)) : 0.f;
    const float wr0 = w9[(dy + 1) * 3 + 0], wr1 = w9[(dy + 1) * 3 + 1], wr2 = w9[(dy + 1) * 3 + 2];
    #pragma unroll
    for (int u = 0; u < 16; ++u)
      conv[u] += vals[u] * wr0 + vals[u + 1] * wr1 + vals[u + 2] * wr2;
  }

  #pragma unroll
  for (int u = 0; u < 16; ++u) {
    const float yv = os[u] / lsum[seg * 16 + u] + conv[u] * sc + bi;
    yt[seg * 16 + u][d] = f2b(yv);
  }
  __syncthreads();

  const int prow = t >> 2, ch = t & 3;
  unsigned short* op = yT + ((size_t)(b * NSP + py * 64 + prow)) * 256 + h * 64 + ch * 16;
  *reinterpret_cast<float4*>(op)     = *reinterpret_cast<const float4*>(&yt[prow][ch * 16]);
  *reinterpret_cast<float4*>(op + 8) = *reinterpret_cast<const float4*>(&yt[prow][ch * 16 + 8]);
}

// ---------------- Kernel 4: MFMA proj GEMM + BN -> out f32 (128-n tiles) ----------------
__global__ __launch_bounds__(256) void proj_gemm_kernel(
    const unsigned short* __restrict__ yT, const unsigned short* __restrict__ wpb,
    const float* __restrict__ gg, const float* __restrict__ bb,
    const float* __restrict__ mm, const float* __restrict__ vv,
    float* __restrict__ out)
{
  const int n0 = blockIdx.x * 128;
  const int co0 = blockIdx.y * 64;   // 4 tiles
  const int b = blockIdx.z;
  const int t = threadIdx.x;
  __shared__ __align__(16) unsigned short wt[64][136];
  __shared__ __align__(16) unsigned short yt[128][136];
  const int lane = t & 63, wave = t >> 6;
  const int m16 = lane & 15, quad = lane >> 4;

  f32x4 acc[8] = {};
  for (int kc = 0; kc < 2; ++kc) {
    if (kc) __syncthreads();
    {
      const unsigned short* wp = wpb + (size_t)(co0 + (t >> 2)) * 256 + kc * 128 + (t & 3) * 32;
      #pragma unroll
      for (int u = 0; u < 4; ++u)
        *reinterpret_cast<float4*>(&wt[t >> 2][(t & 3) * 32 + u * 8]) =
            *reinterpret_cast<const float4*>(wp + u * 8);
      const unsigned short* yp = yT + ((size_t)(b * NSP + n0 + (t >> 1))) * 256 + kc * 128 + (t & 1) * 64;
      #pragma unroll
      for (int u = 0; u < 8; ++u)
        *reinterpret_cast<float4*>(&yt[t >> 1][(t & 1) * 64 + u * 8]) =
            *reinterpret_cast<const float4*>(yp + u * 8);
    }
    __syncthreads();
    #pragma unroll
    for (int ks = 0; ks < 4; ++ks) {
      const short8 bf = *reinterpret_cast<const short8*>(&wt[wave * 16 + m16][ks * 32 + quad * 8]);
      #pragma unroll
      for (int nt = 0; nt < 8; ++nt) {
        const short8 af = *reinterpret_cast<const short8*>(&yt[nt * 16 + m16][ks * 32 + quad * 8]);
        acc[nt] = __builtin_amdgcn_mfma_f32_16x16x32_bf16(af, bf, acc[nt], 0, 0, 0);
      }
    }
  }

  const int c = co0 + wave * 16 + m16;
  const float sc = gg[c] * rsqrtf(vv[c] + BEPS);
  const float bi = bb[c] - mm[c] * sc;
  #pragma unroll
  for (int nt = 0; nt < 8; ++nt) {
    const int n = n0 + nt * 16 + quad * 4;
    float4 ov;
    ov.x = acc[nt][0] * sc + bi; ov.y = acc[nt][1] * sc + bi;
    ov.z = acc[nt][2] * sc + bi; ov.w = acc[nt][3] * sc + bi;
    *reinterpret_cast<float4*>(out + ((size_t)(b * 256 + c)) * NSP + n) = ov;
  }
}

extern "C" void kernel_launch(void* const* d_in, const int* in_sizes, int n_in,
                              void* d_out, int out_size, void* d_ws, size_t ws_size,
                              hipStream_t stream)
{
  const float* x      = (const float*)d_in[0];
  const float* qkv_w  = (const float*)d_in[1];
  const float* qkv_g  = (const float*)d_in[2];
  const float* qkv_b  = (const float*)d_in[3];
  const float* qkv_m  = (const float*)d_in[4];
  const float* qkv_v  = (const float*)d_in[5];
  const float* proj_w = (const float*)d_in[6];
  const float* proj_g = (const float*)d_in[7];
  const float* proj_b = (const float*)d_in[8];
  const float* proj_m = (const float*)d_in[9];
  const float* proj_v = (const float*)d_in[10];
  const float* pe_w   = (const float*)d_in[11];
  const float* pe_g   = (const float*)d_in[12];
  const float* pe_b   = (const float*)d_in[13];
  const float* pe_m   = (const float*)d_in[14];
  const float* pe_v   = (const float*)d_in[15];
  float* out = (float*)d_out;

  unsigned short* qb = (unsigned short*)d_ws;             // 2MB
  unsigned short* kb = qb + (size_t)8 * NSP * 32;         // 2MB
  unsigned short* vb = kb + (size_t)8 * NSP * 32;         // 4MB
  unsigned short* Opart = vb + (size_t)8 * 64 * NSP;      // 16MB
  float* lpart = (float*)(Opart + (size_t)JSPLIT * 8 * 64 * NSP);  // 512KB
  unsigned short* xT = (unsigned short*)(lpart + (size_t)JSPLIT * 8 * NSP);  // 4MB
  unsigned short* yT = xT + (size_t)2 * NSP * 256;        // 4MB
  unsigned short* wqb = yT + (size_t)2 * NSP * 256;       // 256KB
  unsigned short* wpb = wqb + (size_t)512 * 256;          // 128KB

  cast_w_kernel<<<dim3(768), 256, 0, stream>>>(qkv_w, proj_w, wqb, wpb);
  transpose_x_kernel<<<dim3(64, 4, 2), 256, 0, stream>>>(x, xT);
  qkv_gemm_kernel<<<dim3(32, 8, 2), 256, 0, stream>>>(xT, wqb, qkv_g, qkv_b, qkv_m, qkv_v,
                                                      qb, kb, vb);
  attn_kernel<<<dim3(32, 8, JSPLIT), 256, 0, stream>>>(qb, kb, vb, Opart, lpart);
  fuse_kernel<<<dim3(64, 8), 256, 0, stream>>>(Opart, lpart, vb,
                                               pe_w, pe_g, pe_b, pe_m, pe_v, yT);
  proj_gemm_kernel<<<dim3(32, 4, 2), 256, 0, stream>>>(yT, wpb, proj_g, proj_b, proj_m, proj_v,
                                                       out);
}